// Round 1
// baseline (417.319 us; speedup 1.0000x reference)
//
#include <hip/hip_runtime.h>
#include <cmath>
#include <cstdint>

#define NB 8
#define NPROP 1000
#define NCLS 80
#define NLOG 81
#define KCAND 1024
#define NTH 10
#define DFEAT 2048
#define NOBJ 6
#define NSCORE (NPROP*NCLS)   // 80000
#define NPART 20
#define PARTSZ 4000
#define PARTPAD 4096

// ---------------- workspace layout (bytes) ----------------
constexpr size_t OFF_SCORES = 0;
constexpr size_t SZ_SCORES  = (size_t)NB * NSCORE * 4;                 // 2,560,000
constexpr size_t OFF_LISTA  = OFF_SCORES + SZ_SCORES;
constexpr size_t SZ_LISTA   = (size_t)NB * NPART * KCAND * 8;          // 1,310,720
constexpr size_t OFF_CANDK  = OFF_LISTA + SZ_LISTA;
constexpr size_t SZ_CANDK   = (size_t)NB * KCAND * 8;
constexpr size_t OFF_CX1    = OFF_CANDK + SZ_CANDK;
constexpr size_t SZ_CARR    = (size_t)NB * KCAND * 4;
constexpr size_t OFF_CY1    = OFF_CX1 + SZ_CARR;
constexpr size_t OFF_CX2    = OFF_CY1 + SZ_CARR;
constexpr size_t OFF_CY2    = OFF_CX2 + SZ_CARR;
constexpr size_t OFF_CAREA  = OFF_CY2 + SZ_CARR;
constexpr size_t OFF_CPROP  = OFF_CAREA + SZ_CARR;
constexpr size_t OFF_VALIDW = OFF_CPROP + SZ_CARR;
constexpr size_t SZ_VALIDW  = (size_t)NB * 16 * 8;
constexpr size_t OFF_MASKS  = OFF_VALIDW + SZ_VALIDW;
constexpr size_t SZ_MASKS   = (size_t)NTH * NB * KCAND * 16 * 8;       // 10,485,760
constexpr size_t OFF_KEEPS  = OFF_MASKS + SZ_MASKS;
constexpr size_t SZ_KEEPS   = (size_t)NB * NTH * 16 * 8;
constexpr size_t OFF_COUNTS = OFF_KEEPS + SZ_KEEPS;
constexpr size_t SZ_COUNTS  = (size_t)NB * NTH * 4;
constexpr size_t OFF_IDS    = OFF_COUNTS + SZ_COUNTS;

__device__ __forceinline__ float nms_th(int t) {
    // replicates float32(np.arange(0.001, 1.0, 0.1)[t])
    return (float)(0.001 + 0.1 * (double)t);
}

// K1: softmax over 81 logits, one wave per proposal, write 80 probs
__global__ void k_softmax(const float* __restrict__ logits, float* __restrict__ scores) {
    int wid  = (blockIdx.x * blockDim.x + threadIdx.x) >> 6;
    int lane = threadIdx.x & 63;
    if (wid >= NB * NPROP) return;
    const float* L = logits + (size_t)wid * NLOG;
    float l0 = L[lane];
    float l1 = (lane < 17) ? L[64 + lane] : -INFINITY;
    float m = fmaxf(l0, l1);
    #pragma unroll
    for (int o = 32; o > 0; o >>= 1) m = fmaxf(m, __shfl_xor(m, o, 64));
    float e0 = expf(l0 - m);
    float e1 = (lane < 17) ? expf(l1 - m) : 0.f;
    float s = e0 + e1;
    #pragma unroll
    for (int o = 32; o > 0; o >>= 1) s += __shfl_xor(s, o, 64);
    float* outp = scores + (size_t)wid * NCLS;
    outp[lane] = e0 / s;                       // classes 0..63
    if (lane < 16) outp[64 + lane] = e1 / s;   // classes 64..79 (class 80 excluded)
}

// K2: per-partition bitonic sort (4000 real, padded 4096); write sorted top-1024 keys
__global__ __launch_bounds__(1024) void k_psort(const float* __restrict__ scores,
                                                unsigned long long* __restrict__ listA) {
    __shared__ unsigned long long sm[PARTPAD];
    int bimg = blockIdx.x / NPART;
    int p    = blockIdx.x % NPART;
    int tid  = threadIdx.x;
    const float* sc = scores + (size_t)bimg * NSCORE + (size_t)p * PARTSZ;
    for (int k = 0; k < PARTPAD; k += 1024) {
        int t = k + tid;
        unsigned long long key;
        if (t < PARTSZ) {
            float v  = sc[t];
            float vv = (v > 1e-4f) ? v : -1.0f;
            unsigned int bits = __float_as_uint(vv);
            unsigned int u = (bits & 0x80000000u) ? ~bits : (bits | 0x80000000u);
            key = ((unsigned long long)(~u) << 32) | (unsigned int)(p * PARTSZ + t);
        } else {
            key = ~0ULL;
        }
        sm[t] = key;
    }
    __syncthreads();
    for (int k = 2; k <= PARTPAD; k <<= 1) {
        for (int j = k >> 1; j > 0; j >>= 1) {
            for (int i = tid; i < PARTPAD; i += 1024) {
                int ixj = i ^ j;
                if (ixj > i) {
                    bool up = ((i & k) == 0);
                    unsigned long long a = sm[i], b = sm[ixj];
                    if ((a > b) == up) { sm[i] = b; sm[ixj] = a; }
                }
            }
            __syncthreads();
        }
    }
    unsigned long long* outp = listA + ((size_t)bimg * NPART + p) * KCAND;
    outp[tid] = sm[tid];
}

// K3: sequential bitonic merges of 20 sorted lists -> global top-1024 (sorted)
__global__ __launch_bounds__(1024) void k_merge(const unsigned long long* __restrict__ listA,
                                                unsigned long long* __restrict__ candk) {
    __shared__ unsigned long long M[2 * KCAND];
    int bimg = blockIdx.x;
    int q    = threadIdx.x;
    const unsigned long long* base = listA + (size_t)bimg * NPART * KCAND;
    M[q] = base[q];
    for (int p = 1; p < NPART; ++p) {
        __syncthreads();
        M[KCAND + q] = base[(size_t)p * KCAND + (KCAND - 1 - q)];  // reversed -> bitonic
        __syncthreads();
        for (int j = KCAND; j > 0; j >>= 1) {
            int i = ((q & ~(j - 1)) << 1) | (q & (j - 1));
            unsigned long long a = M[i], b = M[i + j];
            if (a > b) { M[i] = b; M[i + j] = a; }
            __syncthreads();
        }
    }
    candk[(size_t)bimg * KCAND + q] = M[q];
}

// K4: candidate prep — clip, class offset, area (all _rn to match numpy per-op rounding)
__global__ __launch_bounds__(1024) void k_cand(const unsigned long long* __restrict__ candk,
                                               const float* __restrict__ boxes,
                                               const int* __restrict__ hw,
                                               float* __restrict__ cx1, float* __restrict__ cy1,
                                               float* __restrict__ cx2, float* __restrict__ cy2,
                                               float* __restrict__ car, int* __restrict__ cprop,
                                               unsigned long long* __restrict__ validw) {
    int bimg = blockIdx.x;
    int j    = threadIdx.x;
    unsigned long long key = candk[(size_t)bimg * KCAND + j];
    unsigned int u   = ~(unsigned int)(key >> 32);
    unsigned int idx = (unsigned int)key;
    const unsigned int uth = __float_as_uint(1e-4f) | 0x80000000u;
    bool valid = u > uth;
    int prop = (int)(idx / NCLS);
    int cls  = (int)(idx - (unsigned)prop * NCLS);
    const float4 bx = *(const float4*)(boxes + ((((size_t)bimg * NPROP + prop) * NCLS + cls) << 2));
    float h = (float)hw[bimg * 2 + 0];
    float w = (float)hw[bimg * 2 + 1];
    float x1 = fminf(fmaxf(bx.x, 0.f), w);
    float y1 = fminf(fmaxf(bx.y, 0.f), h);
    float x2 = fminf(fmaxf(bx.z, 0.f), w);
    float y2 = fminf(fmaxf(bx.w, 0.f), h);
    float offc = __fmul_rn((float)cls, 4096.0f);
    x1 = __fadd_rn(x1, offc); y1 = __fadd_rn(y1, offc);
    x2 = __fadd_rn(x2, offc); y2 = __fadd_rn(y2, offc);
    float area = __fmul_rn(__fsub_rn(x2, x1), __fsub_rn(y2, y1));
    int o = bimg * KCAND + j;
    cx1[o] = x1; cy1[o] = y1; cx2[o] = x2; cy2[o] = y2; car[o] = area; cprop[o] = prop;
    unsigned long long bal = __ballot(valid);
    if ((threadIdx.x & 63) == 0) validw[bimg * 16 + (j >> 6)] = bal;
}

// K5: per-row IoU -> 10 per-threshold suppression bitmask words (j > i enforced)
__global__ void k_masks(const float* __restrict__ cx1, const float* __restrict__ cy1,
                        const float* __restrict__ cx2, const float* __restrict__ cy2,
                        const float* __restrict__ car,
                        unsigned long long* __restrict__ masks) {
    int gw   = (blockIdx.x * blockDim.x + threadIdx.x) >> 6;  // global wave = row
    int lane = threadIdx.x & 63;
    if (gw >= NB * KCAND) return;
    int bimg = gw >> 10;
    int i    = gw & (KCAND - 1);
    int cb   = bimg * KCAND;
    float xi1 = cx1[cb + i], yi1 = cy1[cb + i];
    float xi2 = cx2[cb + i], yi2 = cy2[cb + i], ai = car[cb + i];
    for (int c = 0; c < 16; ++c) {
        int j = c * 64 + lane;
        float xj1 = cx1[cb + j], yj1 = cy1[cb + j];
        float xj2 = cx2[cb + j], yj2 = cy2[cb + j], aj = car[cb + j];
        float iw = fmaxf(__fsub_rn(fminf(xi2, xj2), fmaxf(xi1, xj1)), 0.f);
        float ih = fmaxf(__fsub_rn(fminf(yi2, yj2), fmaxf(yi1, yj1)), 0.f);
        float inter = __fmul_rn(iw, ih);
        float uni   = __fsub_rn(__fadd_rn(ai, aj), inter);
        float iou   = (uni > 0.f) ? __fdiv_rn(inter, uni) : 0.f;
        bool jgt = j > i;
        unsigned long long bl[NTH];
        #pragma unroll
        for (int t = 0; t < NTH; ++t) bl[t] = __ballot(jgt && (iou > nms_th(t)));
        if (lane == 0) {
            #pragma unroll
            for (int t = 0; t < NTH; ++t)
                masks[((((size_t)t * NB + bimg) * KCAND + i) << 4) + c] = bl[t];
        }
    }
}

// K6: greedy NMS bitmask scan, one block per (image, threshold); wave 0 scans
__global__ __launch_bounds__(256) void k_scan(const unsigned long long* __restrict__ masks,
                                              const unsigned long long* __restrict__ validw,
                                              unsigned long long* __restrict__ keeps,
                                              int* __restrict__ counts) {
    __shared__ unsigned long long lm[256 * 16];   // 32 KB: 256 rows staged
    int bt   = blockIdx.x;
    int bimg = bt / NTH, t = bt % NTH;
    int tid  = threadIdx.x;
    int lane = tid & 63;
    unsigned long long keep = 0;
    if (tid < 16) keep = validw[bimg * 16 + tid];
    const unsigned long long* mb = masks + (((size_t)t * NB + bimg) * KCAND << 4);
    for (int s = 0; s < 4; ++s) {
        __syncthreads();
        const unsigned long long* src = mb + ((size_t)s * 256 << 4);
        #pragma unroll
        for (int k = 0; k < 16; ++k) lm[k * 256 + tid] = src[k * 256 + tid];
        __syncthreads();
        if (tid < 64) {
            for (int w = s * 4; w < s * 4 + 4; ++w) {
                int bit = 0;
                while (bit < 64) {
                    unsigned long long kw  = __shfl(keep, w, 64);
                    unsigned long long rem = kw >> bit;
                    if (rem == 0) break;
                    bit += __builtin_ctzll(rem);
                    int r = (w * 64 + bit) - s * 256;
                    if (lane < 16) keep &= ~lm[r * 16 + lane];
                    ++bit;
                }
            }
        }
    }
    if (tid < 64) {
        if (lane < 16) keeps[((size_t)bimg * NTH + t) * 16 + lane] = keep;
        int c = (lane < 16) ? __popcll(keep) : 0;
        #pragma unroll
        for (int o = 32; o > 0; o >>= 1) c += __shfl_xor(c, o, 64);
        if (lane == 0) counts[bimg * NTH + t] = c;
    }
}

// K7: pick first threshold with count>=6 (else last), take first-6 kept (fill with
// lowest-index non-kept if fewer, matching top_k tie order on -inf)
__global__ void k_select(const int* __restrict__ counts,
                         const unsigned long long* __restrict__ keeps,
                         const int* __restrict__ cprop, int* __restrict__ ids) {
    int bimg = blockIdx.x;
    if (threadIdx.x != 0) return;
    int tsel = NTH - 1;
    for (int t = 0; t < NTH; ++t) {
        if (counts[bimg * NTH + t] >= NOBJ) { tsel = t; break; }
    }
    const unsigned long long* kw = keeps + ((size_t)bimg * NTH + tsel) * 16;
    int got = 0;
    for (int k = 0; k < 16 && got < NOBJ; ++k) {
        unsigned long long x = kw[k];
        while (x && got < NOBJ) {
            int b = __builtin_ctzll(x);
            ids[bimg * NOBJ + got] = cprop[bimg * KCAND + k * 64 + b];
            ++got;
            x &= x - 1;
        }
    }
    for (int k = 0; k < 16 && got < NOBJ; ++k) {
        unsigned long long x = ~kw[k];
        while (x && got < NOBJ) {
            int b = __builtin_ctzll(x);
            ids[bimg * NOBJ + got] = cprop[bimg * KCAND + k * 64 + b];
            ++got;
            x &= x - 1;
        }
    }
}

// K8: out[b, d, s] = feats[b, ids[s], d]
__global__ void k_gather(const float* __restrict__ feats, const int* __restrict__ ids,
                         float* __restrict__ outp) {
    int g = blockIdx.x * blockDim.x + threadIdx.x;
    if (g >= NB * DFEAT) return;
    int bimg = g / DFEAT;
    int d    = g - bimg * DFEAT;
    const float* fb = feats + (size_t)bimg * NPROP * DFEAT;
    float* ob = outp + ((size_t)bimg * DFEAT + d) * NOBJ;
    #pragma unroll
    for (int s = 0; s < NOBJ; ++s) {
        int id = ids[bimg * NOBJ + s];
        ob[s] = fb[(size_t)id * DFEAT + d];
    }
}

extern "C" void kernel_launch(void* const* d_in, const int* in_sizes, int n_in,
                              void* d_out, int out_size, void* d_ws, size_t ws_size,
                              hipStream_t stream) {
    const float* logits = (const float*)d_in[0];
    const float* boxes  = (const float*)d_in[1];
    const float* feats  = (const float*)d_in[2];
    const int*   hw     = (const int*)d_in[3];
    float* outp = (float*)d_out;

    char* ws = (char*)d_ws;
    float*              scores = (float*)(ws + OFF_SCORES);
    unsigned long long* listA  = (unsigned long long*)(ws + OFF_LISTA);
    unsigned long long* candk  = (unsigned long long*)(ws + OFF_CANDK);
    float* cx1 = (float*)(ws + OFF_CX1);
    float* cy1 = (float*)(ws + OFF_CY1);
    float* cx2 = (float*)(ws + OFF_CX2);
    float* cy2 = (float*)(ws + OFF_CY2);
    float* car = (float*)(ws + OFF_CAREA);
    int*   cprop = (int*)(ws + OFF_CPROP);
    unsigned long long* validw = (unsigned long long*)(ws + OFF_VALIDW);
    unsigned long long* masks  = (unsigned long long*)(ws + OFF_MASKS);
    unsigned long long* keeps  = (unsigned long long*)(ws + OFF_KEEPS);
    int* counts = (int*)(ws + OFF_COUNTS);
    int* ids    = (int*)(ws + OFF_IDS);

    k_softmax<<<(NB * NPROP) / 4, 256, 0, stream>>>(logits, scores);
    k_psort<<<NB * NPART, 1024, 0, stream>>>(scores, listA);
    k_merge<<<NB, 1024, 0, stream>>>(listA, candk);
    k_cand<<<NB, 1024, 0, stream>>>(candk, boxes, hw, cx1, cy1, cx2, cy2, car, cprop, validw);
    k_masks<<<(NB * KCAND) / 4, 256, 0, stream>>>(cx1, cy1, cx2, cy2, car, masks);
    k_scan<<<NB * NTH, 256, 0, stream>>>(masks, validw, keeps, counts);
    k_select<<<NB, 64, 0, stream>>>(counts, keeps, cprop, ids);
    k_gather<<<(NB * DFEAT + 255) / 256, 256, 0, stream>>>(feats, ids, outp);
}

// Round 3
// 265.722 us; speedup vs baseline: 1.5705x; 1.5705x over previous
//
#include <hip/hip_runtime.h>
#include <cmath>
#include <cstdint>

#define NB 8
#define NPROP 1000
#define NCLS 80
#define NLOG 81
#define KCAND 1024
#define NTH 10
#define DFEAT 2048
#define NOBJ 6
#define NSCORE (NPROP*NCLS)   // 80000
#define NPART 20
#define PARTSZ 4000
#define PARTPAD 4096

// ---------------- workspace layout (bytes) ----------------
constexpr size_t OFF_SCORES = 0;
constexpr size_t SZ_SCORES  = (size_t)NB * NSCORE * 4;                 // 2,560,000
constexpr size_t OFF_LISTA  = OFF_SCORES + SZ_SCORES;
constexpr size_t SZ_LISTA   = (size_t)NB * NPART * KCAND * 8;          // 1,310,720
constexpr size_t OFF_CANDK  = OFF_LISTA + SZ_LISTA;
constexpr size_t SZ_CANDK   = (size_t)NB * KCAND * 8;
constexpr size_t OFF_CX1    = OFF_CANDK + SZ_CANDK;
constexpr size_t SZ_CARR    = (size_t)NB * KCAND * 4;
constexpr size_t OFF_CY1    = OFF_CX1 + SZ_CARR;
constexpr size_t OFF_CX2    = OFF_CY1 + SZ_CARR;
constexpr size_t OFF_CY2    = OFF_CX2 + SZ_CARR;
constexpr size_t OFF_CAREA  = OFF_CY2 + SZ_CARR;
constexpr size_t OFF_CPROP  = OFF_CAREA + SZ_CARR;
constexpr size_t OFF_VALIDW = OFF_CPROP + SZ_CARR;
constexpr size_t SZ_VALIDW  = (size_t)NB * 16 * 8;
constexpr size_t OFF_MASKS  = OFF_VALIDW + SZ_VALIDW;
constexpr size_t SZ_MASKS   = (size_t)NTH * NB * KCAND * 16 * 8;       // 10,485,760
constexpr size_t OFF_KEEPS  = OFF_MASKS + SZ_MASKS;
constexpr size_t SZ_KEEPS   = (size_t)NB * NTH * 16 * 8;
constexpr size_t OFF_COUNTS = OFF_KEEPS + SZ_KEEPS;
constexpr size_t SZ_COUNTS  = (size_t)NB * NTH * 4;
constexpr size_t OFF_IDS    = OFF_COUNTS + SZ_COUNTS;

__device__ __forceinline__ float nms_th(int t) {
    // replicates float32(np.arange(0.001, 1.0, 0.1)[t])
    return (float)(0.001 + 0.1 * (double)t);
}

// K1: softmax over 81 logits, one wave per proposal, write 80 probs
__global__ void k_softmax(const float* __restrict__ logits, float* __restrict__ scores) {
    int wid  = (blockIdx.x * blockDim.x + threadIdx.x) >> 6;
    int lane = threadIdx.x & 63;
    if (wid >= NB * NPROP) return;
    const float* L = logits + (size_t)wid * NLOG;
    float l0 = L[lane];
    float l1 = (lane < 17) ? L[64 + lane] : -INFINITY;
    float m = fmaxf(l0, l1);
    #pragma unroll
    for (int o = 32; o > 0; o >>= 1) m = fmaxf(m, __shfl_xor(m, o, 64));
    float e0 = expf(l0 - m);
    float e1 = (lane < 17) ? expf(l1 - m) : 0.f;
    float s = e0 + e1;
    #pragma unroll
    for (int o = 32; o > 0; o >>= 1) s += __shfl_xor(s, o, 64);
    float* outp = scores + (size_t)wid * NCLS;
    outp[lane] = e0 / s;                       // classes 0..63
    if (lane < 16) outp[64 + lane] = e1 / s;   // classes 64..79 (class 80 excluded)
}

// K2: per-partition bitonic sort (4000 real, padded 4096); write sorted top-1024 keys
__global__ __launch_bounds__(1024) void k_psort(const float* __restrict__ scores,
                                                unsigned long long* __restrict__ listA) {
    __shared__ unsigned long long sm[PARTPAD];
    int bimg = blockIdx.x / NPART;
    int p    = blockIdx.x % NPART;
    int tid  = threadIdx.x;
    const float* sc = scores + (size_t)bimg * NSCORE + (size_t)p * PARTSZ;
    for (int k = 0; k < PARTPAD; k += 1024) {
        int t = k + tid;
        unsigned long long key;
        if (t < PARTSZ) {
            float v  = sc[t];
            float vv = (v > 1e-4f) ? v : -1.0f;
            unsigned int bits = __float_as_uint(vv);
            unsigned int u = (bits & 0x80000000u) ? ~bits : (bits | 0x80000000u);
            key = ((unsigned long long)(~u) << 32) | (unsigned int)(p * PARTSZ + t);
        } else {
            key = ~0ULL;
        }
        sm[t] = key;
    }
    __syncthreads();
    for (int k = 2; k <= PARTPAD; k <<= 1) {
        for (int j = k >> 1; j > 0; j >>= 1) {
            for (int i = tid; i < PARTPAD; i += 1024) {
                int ixj = i ^ j;
                if (ixj > i) {
                    bool up = ((i & k) == 0);
                    unsigned long long a = sm[i], b = sm[ixj];
                    if ((a > b) == up) { sm[i] = b; sm[ixj] = a; }
                }
            }
            __syncthreads();
        }
    }
    unsigned long long* outp = listA + ((size_t)bimg * NPART + p) * KCAND;
    outp[tid] = sm[tid];
}

// K3: sequential bitonic merges of 20 sorted lists -> global top-1024 (sorted)
__global__ __launch_bounds__(1024) void k_merge(const unsigned long long* __restrict__ listA,
                                                unsigned long long* __restrict__ candk) {
    __shared__ unsigned long long M[2 * KCAND];
    int bimg = blockIdx.x;
    int q    = threadIdx.x;
    const unsigned long long* base = listA + (size_t)bimg * NPART * KCAND;
    M[q] = base[q];
    for (int p = 1; p < NPART; ++p) {
        __syncthreads();
        M[KCAND + q] = base[(size_t)p * KCAND + (KCAND - 1 - q)];  // reversed -> bitonic
        __syncthreads();
        for (int j = KCAND; j > 0; j >>= 1) {
            int i = ((q & ~(j - 1)) << 1) | (q & (j - 1));
            unsigned long long a = M[i], b = M[i + j];
            if (a > b) { M[i] = b; M[i + j] = a; }
            __syncthreads();
        }
    }
    candk[(size_t)bimg * KCAND + q] = M[q];
}

// K4: candidate prep — clip, class offset, area (all _rn to match numpy per-op rounding)
__global__ __launch_bounds__(1024) void k_cand(const unsigned long long* __restrict__ candk,
                                               const float* __restrict__ boxes,
                                               const int* __restrict__ hw,
                                               float* __restrict__ cx1, float* __restrict__ cy1,
                                               float* __restrict__ cx2, float* __restrict__ cy2,
                                               float* __restrict__ car, int* __restrict__ cprop,
                                               unsigned long long* __restrict__ validw) {
    int bimg = blockIdx.x;
    int j    = threadIdx.x;
    unsigned long long key = candk[(size_t)bimg * KCAND + j];
    unsigned int u   = ~(unsigned int)(key >> 32);
    unsigned int idx = (unsigned int)key;
    const unsigned int uth = __float_as_uint(1e-4f) | 0x80000000u;
    bool valid = u > uth;
    int prop = (int)(idx / NCLS);
    int cls  = (int)(idx - (unsigned)prop * NCLS);
    const float4 bx = *(const float4*)(boxes + ((((size_t)bimg * NPROP + prop) * NCLS + cls) << 2));
    float h = (float)hw[bimg * 2 + 0];
    float w = (float)hw[bimg * 2 + 1];
    float x1 = fminf(fmaxf(bx.x, 0.f), w);
    float y1 = fminf(fmaxf(bx.y, 0.f), h);
    float x2 = fminf(fmaxf(bx.z, 0.f), w);
    float y2 = fminf(fmaxf(bx.w, 0.f), h);
    float offc = __fmul_rn((float)cls, 4096.0f);
    x1 = __fadd_rn(x1, offc); y1 = __fadd_rn(y1, offc);
    x2 = __fadd_rn(x2, offc); y2 = __fadd_rn(y2, offc);
    float area = __fmul_rn(__fsub_rn(x2, x1), __fsub_rn(y2, y1));
    int o = bimg * KCAND + j;
    cx1[o] = x1; cy1[o] = y1; cx2[o] = x2; cy2[o] = y2; car[o] = area; cprop[o] = prop;
    unsigned long long bal = __ballot(valid);
    if ((threadIdx.x & 63) == 0) validw[bimg * 16 + (j >> 6)] = bal;
}

// K5: per-row IoU -> TRANSPOSED suppression masks: for row i, word c holds bits
// j (in c*64..c*64+63) with j < i and iou(i,j) > thresh  (the suppressors of i).
// Layout word-major: masks[((t*NB+bimg)*16 + c)*KCAND + i] so K6 loads coalesce.
__global__ void k_masks(const float* __restrict__ cx1, const float* __restrict__ cy1,
                        const float* __restrict__ cx2, const float* __restrict__ cy2,
                        const float* __restrict__ car,
                        unsigned long long* __restrict__ masks) {
    int gw   = (blockIdx.x * blockDim.x + threadIdx.x) >> 6;  // global wave = row
    int lane = threadIdx.x & 63;
    if (gw >= NB * KCAND) return;
    int bimg = gw >> 10;
    int i    = gw & (KCAND - 1);
    int cb   = bimg * KCAND;
    float xi1 = cx1[cb + i], yi1 = cy1[cb + i];
    float xi2 = cx2[cb + i], yi2 = cy2[cb + i], ai = car[cb + i];
    for (int c = 0; c < 16; ++c) {
        int j = c * 64 + lane;
        float xj1 = cx1[cb + j], yj1 = cy1[cb + j];
        float xj2 = cx2[cb + j], yj2 = cy2[cb + j], aj = car[cb + j];
        float iw = fmaxf(__fsub_rn(fminf(xi2, xj2), fmaxf(xi1, xj1)), 0.f);
        float ih = fmaxf(__fsub_rn(fminf(yi2, yj2), fmaxf(yi1, yj1)), 0.f);
        float inter = __fmul_rn(iw, ih);
        float uni   = __fsub_rn(__fadd_rn(ai, aj), inter);
        float iou   = (uni > 0.f) ? __fdiv_rn(inter, uni) : 0.f;
        bool jlt = j < i;   // suppressors have smaller index
        unsigned long long bl[NTH];
        #pragma unroll
        for (int t = 0; t < NTH; ++t) bl[t] = __ballot(jlt && (iou > nms_th(t)));
        if (lane == 0) {
            #pragma unroll
            for (int t = 0; t < NTH; ++t)
                masks[((((size_t)t * NB + bimg) * 16 + c) << 10) + i] = bl[t];
        }
    }
}

// K6: greedy NMS via Jacobi fixed-point iteration.
// keep[i] = valid[i] & ~OR_{j<i, iou>t} keep[j]  is strictly triangular, so the
// fixed point is unique and equals the greedy (sequential) solution. Jacobi
// converges in (max suppression-chain depth)+1 iterations; class offsets make
// chains intra-class (~13 cands/class) so expect <~30 iters. Bounded + exact
// fixed-point detection => unconditionally correct.
__global__ __launch_bounds__(1024) void k_scan(const unsigned long long* __restrict__ masks,
                                               const unsigned long long* __restrict__ validw,
                                               unsigned long long* __restrict__ keeps,
                                               int* __restrict__ counts) {
    __shared__ unsigned long long kp[16];
    __shared__ int changed[2];
    int bt   = blockIdx.x;
    int bimg = bt / NTH, t = bt % NTH;
    int tid  = threadIdx.x;
    int w    = tid >> 6;
    int lane = tid & 63;
    // each thread owns row i=tid: its 16-word suppressor bitmask in registers
    const unsigned long long* mb = masks + ((((size_t)t * NB + bimg) * 16) << 10);
    unsigned long long row[16];
    #pragma unroll
    for (int c = 0; c < 16; ++c) row[c] = mb[((size_t)c << 10) + tid];
    unsigned long long vw = validw[bimg * 16 + w];
    bool valid = (vw >> lane) & 1ULL;
    if (tid < 16) kp[tid] = validw[bimg * 16 + tid];
    if (tid < 2) changed[tid] = 0;
    __syncthreads();
    for (int iter = 0; iter < KCAND + 2; ++iter) {
        unsigned long long s = 0;
        #pragma unroll
        for (int c = 0; c < 16; ++c) s |= row[c] & kp[c];
        bool nk = valid && (s == 0);
        unsigned long long bal = __ballot(nk);
        bool diff = (lane == 0) && (bal != kp[w]);
        __syncthreads();                         // all reads of kp done
        if (diff) { kp[w] = bal; changed[iter & 1] = 1; }
        if (tid == 0) changed[(iter + 1) & 1] = 0;   // pre-reset next slot
        __syncthreads();                         // writes visible
        if (!changed[iter & 1]) break;           // uniform read -> uniform break
    }
    if (tid < 16) keeps[((size_t)bimg * NTH + t) * 16 + tid] = kp[tid];
    if (tid < 64) {
        int c = (lane < 16) ? __popcll(kp[lane]) : 0;
        #pragma unroll
        for (int o = 32; o > 0; o >>= 1) c += __shfl_xor(c, o, 64);
        if (lane == 0) counts[bimg * NTH + t] = c;
    }
}

// K7: pick first threshold with count>=6 (else last), take first-6 kept (fill with
// lowest-index non-kept if fewer, matching top_k tie order on -inf)
__global__ void k_select(const int* __restrict__ counts,
                         const unsigned long long* __restrict__ keeps,
                         const int* __restrict__ cprop, int* __restrict__ ids) {
    int bimg = blockIdx.x;
    if (threadIdx.x != 0) return;
    int tsel = NTH - 1;
    for (int t = 0; t < NTH; ++t) {
        if (counts[bimg * NTH + t] >= NOBJ) { tsel = t; break; }
    }
    const unsigned long long* kw = keeps + ((size_t)bimg * NTH + tsel) * 16;
    int got = 0;
    for (int k = 0; k < 16 && got < NOBJ; ++k) {
        unsigned long long x = kw[k];
        while (x && got < NOBJ) {
            int b = __builtin_ctzll(x);
            ids[bimg * NOBJ + got] = cprop[bimg * KCAND + k * 64 + b];
            ++got;
            x &= x - 1;
        }
    }
    for (int k = 0; k < 16 && got < NOBJ; ++k) {
        unsigned long long x = ~kw[k];
        while (x && got < NOBJ) {
            int b = __builtin_ctzll(x);
            ids[bimg * NOBJ + got] = cprop[bimg * KCAND + k * 64 + b];
            ++got;
            x &= x - 1;
        }
    }
}

// K8: out[b, d, s] = feats[b, ids[s], d]
__global__ void k_gather(const float* __restrict__ feats, const int* __restrict__ ids,
                         float* __restrict__ outp) {
    int g = blockIdx.x * blockDim.x + threadIdx.x;
    if (g >= NB * DFEAT) return;
    int bimg = g / DFEAT;
    int d    = g - bimg * DFEAT;
    const float* fb = feats + (size_t)bimg * NPROP * DFEAT;
    float* ob = outp + ((size_t)bimg * DFEAT + d) * NOBJ;
    #pragma unroll
    for (int s = 0; s < NOBJ; ++s) {
        int id = ids[bimg * NOBJ + s];
        ob[s] = fb[(size_t)id * DFEAT + d];
    }
}

extern "C" void kernel_launch(void* const* d_in, const int* in_sizes, int n_in,
                              void* d_out, int out_size, void* d_ws, size_t ws_size,
                              hipStream_t stream) {
    const float* logits = (const float*)d_in[0];
    const float* boxes  = (const float*)d_in[1];
    const float* feats  = (const float*)d_in[2];
    const int*   hw     = (const int*)d_in[3];
    float* outp = (float*)d_out;

    char* ws = (char*)d_ws;
    float*              scores = (float*)(ws + OFF_SCORES);
    unsigned long long* listA  = (unsigned long long*)(ws + OFF_LISTA);
    unsigned long long* candk  = (unsigned long long*)(ws + OFF_CANDK);
    float* cx1 = (float*)(ws + OFF_CX1);
    float* cy1 = (float*)(ws + OFF_CY1);
    float* cx2 = (float*)(ws + OFF_CX2);
    float* cy2 = (float*)(ws + OFF_CY2);
    float* car = (float*)(ws + OFF_CAREA);
    int*   cprop = (int*)(ws + OFF_CPROP);
    unsigned long long* validw = (unsigned long long*)(ws + OFF_VALIDW);
    unsigned long long* masks  = (unsigned long long*)(ws + OFF_MASKS);
    unsigned long long* keeps  = (unsigned long long*)(ws + OFF_KEEPS);
    int* counts = (int*)(ws + OFF_COUNTS);
    int* ids    = (int*)(ws + OFF_IDS);

    k_softmax<<<(NB * NPROP) / 4, 256, 0, stream>>>(logits, scores);
    k_psort<<<NB * NPART, 1024, 0, stream>>>(scores, listA);
    k_merge<<<NB, 1024, 0, stream>>>(listA, candk);
    k_cand<<<NB, 1024, 0, stream>>>(candk, boxes, hw, cx1, cy1, cx2, cy2, car, cprop, validw);
    k_masks<<<(NB * KCAND) / 4, 256, 0, stream>>>(cx1, cy1, cx2, cy2, car, masks);
    k_scan<<<NB * NTH, 1024, 0, stream>>>(masks, validw, keeps, counts);
    k_select<<<NB, 64, 0, stream>>>(counts, keeps, cprop, ids);
    k_gather<<<(NB * DFEAT + 255) / 256, 256, 0, stream>>>(feats, ids, outp);
}

// Round 4
// 227.433 us; speedup vs baseline: 1.8349x; 1.1684x over previous
//
#include <hip/hip_runtime.h>
#include <cmath>
#include <cstdint>

#define NB 8
#define NPROP 1000
#define NCLS 80
#define NLOG 81
#define KCAND 1024
#define NTH 10
#define DFEAT 2048
#define NOBJ 6
#define NSCORE (NPROP*NCLS)   // 80000
#define HBLK 8                // histogram/gather blocks per image
#define HCHUNK (NSCORE/HBLK)  // 10000 elements per block

// ---------------- workspace layout (bytes) ----------------
constexpr size_t OFF_SCORES = 0;
constexpr size_t SZ_SCORES  = (size_t)NB * NSCORE * 4;                 // 2,560,000
constexpr size_t OFF_LISTA  = OFF_SCORES + SZ_SCORES;                  // reused region:
constexpr size_t SZ_LISTA   = (size_t)NB * 20 * KCAND * 8;             // 1,310,720 capacity
//   radix-select sub-buffers inside the old LISTA extent:
constexpr size_t OFF_H1     = OFF_LISTA;                               // 8*8*2048*4 = 524,288
constexpr size_t OFF_H2     = OFF_H1 + (size_t)NB * HBLK * 2048 * 4;   // 524,288
constexpr size_t OFF_PIV    = OFF_H2 + (size_t)NB * HBLK * 2048 * 4;   // 8*8*4 = 256
constexpr size_t OFF_CBUF   = OFF_PIV + (size_t)NB * 8 * 4;            // 8*2048*8 = 131,072
// (total 1,179,904 <= SZ_LISTA)
constexpr size_t OFF_CANDK  = OFF_LISTA + SZ_LISTA;
constexpr size_t SZ_CANDK   = (size_t)NB * KCAND * 8;
constexpr size_t OFF_CX1    = OFF_CANDK + SZ_CANDK;
constexpr size_t SZ_CARR    = (size_t)NB * KCAND * 4;
constexpr size_t OFF_CY1    = OFF_CX1 + SZ_CARR;
constexpr size_t OFF_CX2    = OFF_CY1 + SZ_CARR;
constexpr size_t OFF_CY2    = OFF_CX2 + SZ_CARR;
constexpr size_t OFF_CAREA  = OFF_CY2 + SZ_CARR;
constexpr size_t OFF_CPROP  = OFF_CAREA + SZ_CARR;
constexpr size_t OFF_VALIDW = OFF_CPROP + SZ_CARR;
constexpr size_t SZ_VALIDW  = (size_t)NB * 16 * 8;
constexpr size_t OFF_MASKS  = OFF_VALIDW + SZ_VALIDW;
constexpr size_t SZ_MASKS   = (size_t)NTH * NB * KCAND * 16 * 8;       // 10,485,760
constexpr size_t OFF_KEEPS  = OFF_MASKS + SZ_MASKS;
constexpr size_t SZ_KEEPS   = (size_t)NB * NTH * 16 * 8;
constexpr size_t OFF_COUNTS = OFF_KEEPS + SZ_KEEPS;
constexpr size_t SZ_COUNTS  = (size_t)NB * NTH * 4;
constexpr size_t OFF_IDS    = OFF_COUNTS + SZ_COUNTS;

__device__ __forceinline__ float nms_th(int t) {
    // replicates float32(np.arange(0.001, 1.0, 0.1)[t])
    return (float)(0.001 + 0.1 * (double)t);
}

// monotone key: ascending u64 order == (score desc, flat idx asc) == lax.top_k order
__device__ __forceinline__ unsigned score_vkey(float v) {
    float vv = (v > 1e-4f) ? v : -1.0f;
    unsigned bits = __float_as_uint(vv);
    unsigned u = (bits & 0x80000000u) ? ~bits : (bits | 0x80000000u);  // ascending by value
    return ~u;                                                          // ascending = score desc
}

// K1: softmax over 81 logits, one wave per proposal, write 80 probs
__global__ void k_softmax(const float* __restrict__ logits, float* __restrict__ scores) {
    int wid  = (blockIdx.x * blockDim.x + threadIdx.x) >> 6;
    int lane = threadIdx.x & 63;
    if (wid >= NB * NPROP) return;
    const float* L = logits + (size_t)wid * NLOG;
    float l0 = L[lane];
    float l1 = (lane < 17) ? L[64 + lane] : -INFINITY;
    float m = fmaxf(l0, l1);
    #pragma unroll
    for (int o = 32; o > 0; o >>= 1) m = fmaxf(m, __shfl_xor(m, o, 64));
    float e0 = expf(l0 - m);
    float e1 = (lane < 17) ? expf(l1 - m) : 0.f;
    float s = e0 + e1;
    #pragma unroll
    for (int o = 32; o > 0; o >>= 1) s += __shfl_xor(s, o, 64);
    float* outp = scores + (size_t)wid * NCLS;
    outp[lane] = e0 / s;                       // classes 0..63
    if (lane < 16) outp[64 + lane] = e1 / s;   // classes 64..79 (class 80 excluded)
}

// K2a: level-1 histogram (vkey bits [31:21], 2048 bins), private per-block global slices
__global__ __launch_bounds__(1024) void k_hist1(const float* __restrict__ scores,
                                                unsigned* __restrict__ hist1) {
    __shared__ unsigned hh[2048];
    int img = blockIdx.x >> 3, blk = blockIdx.x & 7;
    int tid = threadIdx.x;
    hh[tid] = 0; hh[tid + 1024] = 0;
    __syncthreads();
    const float* sc = scores + (size_t)img * NSCORE + (size_t)blk * HCHUNK;
    for (int e = tid; e < HCHUNK; e += 1024) {
        unsigned vk = score_vkey(sc[e]);
        atomicAdd(&hh[vk >> 21], 1u);
    }
    __syncthreads();
    unsigned* outp = hist1 + ((size_t)img * HBLK + blk) * 2048;
    outp[tid] = hh[tid];
    outp[tid + 1024] = hh[tid + 1024];
}

// block-wide: sum 8 sub-hists, inclusive scan of 2048 bins, find crossing bin for rank K
__device__ __forceinline__ void pivot_scan(const unsigned* __restrict__ h8, unsigned K,
                                           int* __restrict__ out_b, int* __restrict__ out_rem) {
    __shared__ unsigned wsum[16];
    int tid = threadIdx.x;
    unsigned a = 0, b = 0;
    #pragma unroll
    for (int s = 0; s < HBLK; ++s) {
        a += h8[s * 2048 + 2 * tid];
        b += h8[s * 2048 + 2 * tid + 1];
    }
    unsigned p = a + b;
    unsigned x = p;
    #pragma unroll
    for (int d = 1; d < 64; d <<= 1) {
        unsigned y = __shfl_up(x, (unsigned)d, 64);
        if ((tid & 63) >= d) x += y;
    }
    if ((tid & 63) == 63) wsum[tid >> 6] = x;
    __syncthreads();
    if (tid < 16) {
        unsigned w = wsum[tid];
        #pragma unroll
        for (int d = 1; d < 16; d <<= 1) {
            unsigned y = __shfl_up(w, (unsigned)d, 64);
            if (tid >= d) w += y;
        }
        wsum[tid] = w;  // inclusive wave sums
    }
    __syncthreads();
    unsigned wex = (tid >= 64) ? wsum[(tid >> 6) - 1] : 0u;
    unsigned incl = x + wex;       // inclusive pair-sum prefix at this thread
    unsigned E = incl - p;         // exclusive prefix before bin 2*tid
    if (E < K && E + a >= K)              { *out_b = 2 * tid;     *out_rem = (int)(K - E); }
    else if (E + a < K && E + a + b >= K) { *out_b = 2 * tid + 1; *out_rem = (int)(K - (E + a)); }
}

// K2b: find level-1 pivot bin b1 and residual rank K2
__global__ __launch_bounds__(1024) void k_pivot1(const unsigned* __restrict__ hist1,
                                                 int* __restrict__ piv) {
    int img = blockIdx.x;
    pivot_scan(hist1 + (size_t)img * HBLK * 2048, KCAND,
               &piv[img * 8 + 0], &piv[img * 8 + 1]);
}

// K2c: level-2 histogram (vkey bits [20:10]) restricted to elements in bin b1
__global__ __launch_bounds__(1024) void k_hist2(const float* __restrict__ scores,
                                                const int* __restrict__ piv,
                                                unsigned* __restrict__ hist2) {
    __shared__ unsigned hh[2048];
    int img = blockIdx.x >> 3, blk = blockIdx.x & 7;
    int tid = threadIdx.x;
    hh[tid] = 0; hh[tid + 1024] = 0;
    __syncthreads();
    unsigned b1 = (unsigned)piv[img * 8 + 0];
    const float* sc = scores + (size_t)img * NSCORE + (size_t)blk * HCHUNK;
    for (int e = tid; e < HCHUNK; e += 1024) {
        unsigned vk = score_vkey(sc[e]);
        if ((vk >> 21) == b1) atomicAdd(&hh[(vk >> 10) & 2047u], 1u);
    }
    __syncthreads();
    unsigned* outp = hist2 + ((size_t)img * HBLK + blk) * 2048;
    outp[tid] = hh[tid];
    outp[tid + 1024] = hh[tid + 1024];
}

// K2d: find level-2 pivot -> 22-bit threshold T22; zero the gather counter
__global__ __launch_bounds__(1024) void k_pivot2(const unsigned* __restrict__ hist2,
                                                 int* __restrict__ piv) {
    __shared__ int b2s, rem2s;
    int img = blockIdx.x;
    pivot_scan(hist2 + (size_t)img * HBLK * 2048, (unsigned)piv[img * 8 + 1], &b2s, &rem2s);
    __syncthreads();
    if (threadIdx.x == 0) {
        piv[img * 8 + 2] = (piv[img * 8 + 0] << 11) | b2s;  // T22
        piv[img * 8 + 3] = 0;                               // gather counter
    }
}

// K2e: gather all elements with top22(key) <= T22 (>=1024, ~1030 expected), unordered
__global__ __launch_bounds__(1024) void k_gathersel(const float* __restrict__ scores,
                                                    int* __restrict__ piv,
                                                    unsigned long long* __restrict__ cbuf) {
    __shared__ unsigned lcnt, gbase;
    int img = blockIdx.x >> 3, blk = blockIdx.x & 7;
    int tid = threadIdx.x;
    if (tid == 0) lcnt = 0;
    __syncthreads();
    unsigned T22 = (unsigned)piv[img * 8 + 2];
    const float* sc = scores + (size_t)img * NSCORE + (size_t)blk * HCHUNK;
    unsigned long long sel[(HCHUNK + 1023) / 1024];
    int ns = 0;
    for (int e = tid; e < HCHUNK; e += 1024) {
        unsigned vk = score_vkey(sc[e]);
        if ((vk >> 10) <= T22)
            sel[ns++] = ((unsigned long long)vk << 32) | (unsigned)(blk * HCHUNK + e);
    }
    unsigned lp = atomicAdd(&lcnt, (unsigned)ns);
    __syncthreads();
    if (tid == 0) gbase = atomicAdd((unsigned*)&piv[img * 8 + 3], lcnt);
    __syncthreads();
    unsigned long long* ob = cbuf + (size_t)img * 2048;
    for (int i = 0; i < ns; ++i) {
        unsigned pos = gbase + lp + (unsigned)i;
        if (pos < 2048) ob[pos] = sel[i];
    }
}

// K2f: rank-by-counting -> sorted top-1024 keys. Broadcast LDS loop: all lanes read
// the same keys[j] (conflict-free broadcast). rank<1024 scatters into candk.
__global__ __launch_bounds__(1024) void k_rank(const unsigned long long* __restrict__ cbuf,
                                               const int* __restrict__ piv,
                                               unsigned long long* __restrict__ candk) {
    __shared__ unsigned long long keys[2048];
    int img = blockIdx.x >> 1, half = blockIdx.x & 1;
    int tid = threadIdx.x;
    int cnt = piv[img * 8 + 3]; if (cnt > 2048) cnt = 2048;
    const unsigned long long* ib = cbuf + (size_t)img * 2048;
    keys[tid]        = (tid < cnt)        ? ib[tid]        : ~0ULL;
    keys[tid + 1024] = (tid + 1024 < cnt) ? ib[tid + 1024] : ~0ULL;
    __syncthreads();
    unsigned long long a = keys[half * 1024 + tid];
    int r = 0;
    #pragma unroll 4
    for (int j = 0; j < 2048; ++j) r += (keys[j] < a) ? 1 : 0;
    if (r < KCAND) candk[(size_t)img * KCAND + r] = a;
}

// K4: candidate prep — clip, class offset, area (all _rn to match numpy per-op rounding)
__global__ __launch_bounds__(1024) void k_cand(const unsigned long long* __restrict__ candk,
                                               const float* __restrict__ boxes,
                                               const int* __restrict__ hw,
                                               float* __restrict__ cx1, float* __restrict__ cy1,
                                               float* __restrict__ cx2, float* __restrict__ cy2,
                                               float* __restrict__ car, int* __restrict__ cprop,
                                               unsigned long long* __restrict__ validw) {
    int bimg = blockIdx.x;
    int j    = threadIdx.x;
    unsigned long long key = candk[(size_t)bimg * KCAND + j];
    unsigned int u   = ~(unsigned int)(key >> 32);
    unsigned int idx = (unsigned int)key;
    const unsigned int uth = __float_as_uint(1e-4f) | 0x80000000u;
    bool valid = u > uth;
    int prop = (int)(idx / NCLS);
    int cls  = (int)(idx - (unsigned)prop * NCLS);
    const float4 bx = *(const float4*)(boxes + ((((size_t)bimg * NPROP + prop) * NCLS + cls) << 2));
    float h = (float)hw[bimg * 2 + 0];
    float w = (float)hw[bimg * 2 + 1];
    float x1 = fminf(fmaxf(bx.x, 0.f), w);
    float y1 = fminf(fmaxf(bx.y, 0.f), h);
    float x2 = fminf(fmaxf(bx.z, 0.f), w);
    float y2 = fminf(fmaxf(bx.w, 0.f), h);
    float offc = __fmul_rn((float)cls, 4096.0f);
    x1 = __fadd_rn(x1, offc); y1 = __fadd_rn(y1, offc);
    x2 = __fadd_rn(x2, offc); y2 = __fadd_rn(y2, offc);
    float area = __fmul_rn(__fsub_rn(x2, x1), __fsub_rn(y2, y1));
    int o = bimg * KCAND + j;
    cx1[o] = x1; cy1[o] = y1; cx2[o] = x2; cy2[o] = y2; car[o] = area; cprop[o] = prop;
    unsigned long long bal = __ballot(valid);
    if ((threadIdx.x & 63) == 0) validw[bimg * 16 + (j >> 6)] = bal;
}

// K5: per-row IoU -> TRANSPOSED suppression masks: for row i, word c holds bits
// j (in c*64..c*64+63) with j < i and iou(i,j) > thresh  (the suppressors of i).
// Layout word-major: masks[((t*NB+bimg)*16 + c)*KCAND + i] so K6 loads coalesce.
__global__ void k_masks(const float* __restrict__ cx1, const float* __restrict__ cy1,
                        const float* __restrict__ cx2, const float* __restrict__ cy2,
                        const float* __restrict__ car,
                        unsigned long long* __restrict__ masks) {
    int gw   = (blockIdx.x * blockDim.x + threadIdx.x) >> 6;  // global wave = row
    int lane = threadIdx.x & 63;
    if (gw >= NB * KCAND) return;
    int bimg = gw >> 10;
    int i    = gw & (KCAND - 1);
    int cb   = bimg * KCAND;
    float xi1 = cx1[cb + i], yi1 = cy1[cb + i];
    float xi2 = cx2[cb + i], yi2 = cy2[cb + i], ai = car[cb + i];
    for (int c = 0; c < 16; ++c) {
        int j = c * 64 + lane;
        float xj1 = cx1[cb + j], yj1 = cy1[cb + j];
        float xj2 = cx2[cb + j], yj2 = cy2[cb + j], aj = car[cb + j];
        float iw = fmaxf(__fsub_rn(fminf(xi2, xj2), fmaxf(xi1, xj1)), 0.f);
        float ih = fmaxf(__fsub_rn(fminf(yi2, yj2), fmaxf(yi1, yj1)), 0.f);
        float inter = __fmul_rn(iw, ih);
        float uni   = __fsub_rn(__fadd_rn(ai, aj), inter);
        float iou   = (uni > 0.f) ? __fdiv_rn(inter, uni) : 0.f;
        bool jlt = j < i;   // suppressors have smaller index
        unsigned long long bl[NTH];
        #pragma unroll
        for (int t = 0; t < NTH; ++t) bl[t] = __ballot(jlt && (iou > nms_th(t)));
        if (lane == 0) {
            #pragma unroll
            for (int t = 0; t < NTH; ++t)
                masks[((((size_t)t * NB + bimg) * 16 + c) << 10) + i] = bl[t];
        }
    }
}

// K6: greedy NMS via Jacobi fixed-point iteration (exact greedy fixed point).
__global__ __launch_bounds__(1024) void k_scan(const unsigned long long* __restrict__ masks,
                                               const unsigned long long* __restrict__ validw,
                                               unsigned long long* __restrict__ keeps,
                                               int* __restrict__ counts) {
    __shared__ unsigned long long kp[16];
    __shared__ int changed[2];
    int bt   = blockIdx.x;
    int bimg = bt / NTH, t = bt % NTH;
    int tid  = threadIdx.x;
    int w    = tid >> 6;
    int lane = tid & 63;
    const unsigned long long* mb = masks + ((((size_t)t * NB + bimg) * 16) << 10);
    unsigned long long row[16];
    #pragma unroll
    for (int c = 0; c < 16; ++c) row[c] = mb[((size_t)c << 10) + tid];
    unsigned long long vw = validw[bimg * 16 + w];
    bool valid = (vw >> lane) & 1ULL;
    if (tid < 16) kp[tid] = validw[bimg * 16 + tid];
    if (tid < 2) changed[tid] = 0;
    __syncthreads();
    for (int iter = 0; iter < KCAND + 2; ++iter) {
        unsigned long long s = 0;
        #pragma unroll
        for (int c = 0; c < 16; ++c) s |= row[c] & kp[c];
        bool nk = valid && (s == 0);
        unsigned long long bal = __ballot(nk);
        bool diff = (lane == 0) && (bal != kp[w]);
        __syncthreads();
        if (diff) { kp[w] = bal; changed[iter & 1] = 1; }
        if (tid == 0) changed[(iter + 1) & 1] = 0;
        __syncthreads();
        if (!changed[iter & 1]) break;
    }
    if (tid < 16) keeps[((size_t)bimg * NTH + t) * 16 + tid] = kp[tid];
    if (tid < 64) {
        int c = (lane < 16) ? __popcll(kp[lane]) : 0;
        #pragma unroll
        for (int o = 32; o > 0; o >>= 1) c += __shfl_xor(c, o, 64);
        if (lane == 0) counts[bimg * NTH + t] = c;
    }
}

// K7: pick first threshold with count>=6 (else last), take first-6 kept (fill with
// lowest-index non-kept if fewer, matching top_k tie order on -inf)
__global__ void k_select(const int* __restrict__ counts,
                         const unsigned long long* __restrict__ keeps,
                         const int* __restrict__ cprop, int* __restrict__ ids) {
    int bimg = blockIdx.x;
    if (threadIdx.x != 0) return;
    int tsel = NTH - 1;
    for (int t = 0; t < NTH; ++t) {
        if (counts[bimg * NTH + t] >= NOBJ) { tsel = t; break; }
    }
    const unsigned long long* kw = keeps + ((size_t)bimg * NTH + tsel) * 16;
    int got = 0;
    for (int k = 0; k < 16 && got < NOBJ; ++k) {
        unsigned long long x = kw[k];
        while (x && got < NOBJ) {
            int b = __builtin_ctzll(x);
            ids[bimg * NOBJ + got] = cprop[bimg * KCAND + k * 64 + b];
            ++got;
            x &= x - 1;
        }
    }
    for (int k = 0; k < 16 && got < NOBJ; ++k) {
        unsigned long long x = ~kw[k];
        while (x && got < NOBJ) {
            int b = __builtin_ctzll(x);
            ids[bimg * NOBJ + got] = cprop[bimg * KCAND + k * 64 + b];
            ++got;
            x &= x - 1;
        }
    }
}

// K8: out[b, d, s] = feats[b, ids[s], d]
__global__ void k_featgather(const float* __restrict__ feats, const int* __restrict__ ids,
                             float* __restrict__ outp) {
    int g = blockIdx.x * blockDim.x + threadIdx.x;
    if (g >= NB * DFEAT) return;
    int bimg = g / DFEAT;
    int d    = g - bimg * DFEAT;
    const float* fb = feats + (size_t)bimg * NPROP * DFEAT;
    float* ob = outp + ((size_t)bimg * DFEAT + d) * NOBJ;
    #pragma unroll
    for (int s = 0; s < NOBJ; ++s) {
        int id = ids[bimg * NOBJ + s];
        ob[s] = fb[(size_t)id * DFEAT + d];
    }
}

extern "C" void kernel_launch(void* const* d_in, const int* in_sizes, int n_in,
                              void* d_out, int out_size, void* d_ws, size_t ws_size,
                              hipStream_t stream) {
    const float* logits = (const float*)d_in[0];
    const float* boxes  = (const float*)d_in[1];
    const float* feats  = (const float*)d_in[2];
    const int*   hw     = (const int*)d_in[3];
    float* outp = (float*)d_out;

    char* ws = (char*)d_ws;
    float*              scores = (float*)(ws + OFF_SCORES);
    unsigned*           hist1  = (unsigned*)(ws + OFF_H1);
    unsigned*           hist2  = (unsigned*)(ws + OFF_H2);
    int*                piv    = (int*)(ws + OFF_PIV);
    unsigned long long* cbuf   = (unsigned long long*)(ws + OFF_CBUF);
    unsigned long long* candk  = (unsigned long long*)(ws + OFF_CANDK);
    float* cx1 = (float*)(ws + OFF_CX1);
    float* cy1 = (float*)(ws + OFF_CY1);
    float* cx2 = (float*)(ws + OFF_CX2);
    float* cy2 = (float*)(ws + OFF_CY2);
    float* car = (float*)(ws + OFF_CAREA);
    int*   cprop = (int*)(ws + OFF_CPROP);
    unsigned long long* validw = (unsigned long long*)(ws + OFF_VALIDW);
    unsigned long long* masks  = (unsigned long long*)(ws + OFF_MASKS);
    unsigned long long* keeps  = (unsigned long long*)(ws + OFF_KEEPS);
    int* counts = (int*)(ws + OFF_COUNTS);
    int* ids    = (int*)(ws + OFF_IDS);

    k_softmax<<<(NB * NPROP) / 4, 256, 0, stream>>>(logits, scores);
    k_hist1<<<NB * HBLK, 1024, 0, stream>>>(scores, hist1);
    k_pivot1<<<NB, 1024, 0, stream>>>(hist1, piv);
    k_hist2<<<NB * HBLK, 1024, 0, stream>>>(scores, piv, hist2);
    k_pivot2<<<NB, 1024, 0, stream>>>(hist2, piv);
    k_gathersel<<<NB * HBLK, 1024, 0, stream>>>(scores, piv, cbuf);
    k_rank<<<NB * 2, 1024, 0, stream>>>(cbuf, piv, candk);
    k_cand<<<NB, 1024, 0, stream>>>(candk, boxes, hw, cx1, cy1, cx2, cy2, car, cprop, validw);
    k_masks<<<(NB * KCAND) / 4, 256, 0, stream>>>(cx1, cy1, cx2, cy2, car, masks);
    k_scan<<<NB * NTH, 1024, 0, stream>>>(masks, validw, keeps, counts);
    k_select<<<NB, 64, 0, stream>>>(counts, keeps, cprop, ids);
    k_featgather<<<(NB * DFEAT + 255) / 256, 256, 0, stream>>>(feats, ids, outp);
}

// Round 5
// 168.600 us; speedup vs baseline: 2.4752x; 1.3489x over previous
//
#include <hip/hip_runtime.h>
#include <cmath>
#include <cstdint>

#define NB 8
#define NPROP 1000
#define NCLS 80
#define NLOG 81
#define KCAND 1024
#define NTH 10
#define DFEAT 2048
#define NOBJ 6
#define NSCORE (NPROP*NCLS)   // 80000
#define HBLK 8                // histogram/gather blocks per image
#define HCHUNK (NSCORE/HBLK)  // 10000 elements per block

// ---------------- workspace layout (bytes) ----------------
constexpr size_t OFF_SCORES = 0;
constexpr size_t SZ_SCORES  = (size_t)NB * NSCORE * 4;                 // 2,560,000
constexpr size_t OFF_LISTA  = OFF_SCORES + SZ_SCORES;                  // reused region:
constexpr size_t SZ_LISTA   = (size_t)NB * 20 * KCAND * 8;             // 1,310,720 capacity
constexpr size_t OFF_H1     = OFF_LISTA;                               // 8*8*2048*4 = 524,288
constexpr size_t OFF_H2     = OFF_H1 + (size_t)NB * HBLK * 2048 * 4;   // 524,288
constexpr size_t OFF_PIV    = OFF_H2 + (size_t)NB * HBLK * 2048 * 4;   // 8*8*4 = 256
constexpr size_t OFF_CBUF   = OFF_PIV + (size_t)NB * 8 * 4;            // 8*2048*8 = 131,072
constexpr size_t OFF_CANDK  = OFF_LISTA + SZ_LISTA;
constexpr size_t SZ_CANDK   = (size_t)NB * KCAND * 8;
constexpr size_t OFF_CX1    = OFF_CANDK + SZ_CANDK;
constexpr size_t SZ_CARR    = (size_t)NB * KCAND * 4;
constexpr size_t OFF_CY1    = OFF_CX1 + SZ_CARR;
constexpr size_t OFF_CX2    = OFF_CY1 + SZ_CARR;
constexpr size_t OFF_CY2    = OFF_CX2 + SZ_CARR;
constexpr size_t OFF_CAREA  = OFF_CY2 + SZ_CARR;
constexpr size_t OFF_CPROP  = OFF_CAREA + SZ_CARR;
constexpr size_t OFF_VALIDW = OFF_CPROP + SZ_CARR;
constexpr size_t SZ_VALIDW  = (size_t)NB * 16 * 8;
constexpr size_t OFF_MASKS  = OFF_VALIDW + SZ_VALIDW;
constexpr size_t SZ_MASKS   = (size_t)NTH * NB * KCAND * 16 * 8;       // 10,485,760
constexpr size_t OFF_KEEPS  = OFF_MASKS + SZ_MASKS;
constexpr size_t SZ_KEEPS   = (size_t)NB * NTH * 16 * 8;
constexpr size_t OFF_COUNTS = OFF_KEEPS + SZ_KEEPS;
constexpr size_t SZ_COUNTS  = (size_t)NB * NTH * 4;
constexpr size_t OFF_IDS    = OFF_COUNTS + SZ_COUNTS;

// per-threshold word stride in the masks array
#define TSTRIDE ((size_t)NB * 16 * 1024)

__device__ __forceinline__ float nms_th(int t) {
    // replicates float32(np.arange(0.001, 1.0, 0.1)[t])
    return (float)(0.001 + 0.1 * (double)t);
}

// monotone key: ascending u64 order == (score desc, flat idx asc) == lax.top_k order
__device__ __forceinline__ unsigned score_vkey(float v) {
    float vv = (v > 1e-4f) ? v : -1.0f;
    unsigned bits = __float_as_uint(vv);
    unsigned u = (bits & 0x80000000u) ? ~bits : (bits | 0x80000000u);  // ascending by value
    return ~u;                                                          // ascending = score desc
}

// K0: zero the masks array (re-poisoned 0xAA before every launch) so k_masks
// only has to store non-zero chunks.
__global__ void k_memz(ulonglong2* __restrict__ p, int n) {
    int g = blockIdx.x * blockDim.x + threadIdx.x;
    if (g < n) p[g] = ulonglong2{0ULL, 0ULL};
}

// K1: softmax over 81 logits, one wave per proposal, write 80 probs
__global__ void k_softmax(const float* __restrict__ logits, float* __restrict__ scores) {
    int wid  = (blockIdx.x * blockDim.x + threadIdx.x) >> 6;
    int lane = threadIdx.x & 63;
    if (wid >= NB * NPROP) return;
    const float* L = logits + (size_t)wid * NLOG;
    float l0 = L[lane];
    float l1 = (lane < 17) ? L[64 + lane] : -INFINITY;
    float m = fmaxf(l0, l1);
    #pragma unroll
    for (int o = 32; o > 0; o >>= 1) m = fmaxf(m, __shfl_xor(m, o, 64));
    float e0 = expf(l0 - m);
    float e1 = (lane < 17) ? expf(l1 - m) : 0.f;
    float s = e0 + e1;
    #pragma unroll
    for (int o = 32; o > 0; o >>= 1) s += __shfl_xor(s, o, 64);
    float* outp = scores + (size_t)wid * NCLS;
    outp[lane] = e0 / s;                       // classes 0..63
    if (lane < 16) outp[64 + lane] = e1 / s;   // classes 64..79 (class 80 excluded)
}

// K2a: level-1 histogram (vkey bits [31:21], 2048 bins), private per-block global slices
__global__ __launch_bounds__(1024) void k_hist1(const float* __restrict__ scores,
                                                unsigned* __restrict__ hist1) {
    __shared__ unsigned hh[2048];
    int img = blockIdx.x >> 3, blk = blockIdx.x & 7;
    int tid = threadIdx.x;
    hh[tid] = 0; hh[tid + 1024] = 0;
    __syncthreads();
    const float* sc = scores + (size_t)img * NSCORE + (size_t)blk * HCHUNK;
    for (int e = tid; e < HCHUNK; e += 1024) {
        unsigned vk = score_vkey(sc[e]);
        atomicAdd(&hh[vk >> 21], 1u);
    }
    __syncthreads();
    unsigned* outp = hist1 + ((size_t)img * HBLK + blk) * 2048;
    outp[tid] = hh[tid];
    outp[tid + 1024] = hh[tid + 1024];
}

// block-wide: sum 8 sub-hists, inclusive scan of 2048 bins, find crossing bin for rank K
__device__ __forceinline__ void pivot_scan(const unsigned* __restrict__ h8, unsigned K,
                                           int* __restrict__ out_b, int* __restrict__ out_rem) {
    __shared__ unsigned wsum[16];
    int tid = threadIdx.x;
    unsigned a = 0, b = 0;
    #pragma unroll
    for (int s = 0; s < HBLK; ++s) {
        a += h8[s * 2048 + 2 * tid];
        b += h8[s * 2048 + 2 * tid + 1];
    }
    unsigned p = a + b;
    unsigned x = p;
    #pragma unroll
    for (int d = 1; d < 64; d <<= 1) {
        unsigned y = __shfl_up(x, (unsigned)d, 64);
        if ((tid & 63) >= d) x += y;
    }
    if ((tid & 63) == 63) wsum[tid >> 6] = x;
    __syncthreads();
    if (tid < 16) {
        unsigned w = wsum[tid];
        #pragma unroll
        for (int d = 1; d < 16; d <<= 1) {
            unsigned y = __shfl_up(w, (unsigned)d, 64);
            if (tid >= d) w += y;
        }
        wsum[tid] = w;  // inclusive wave sums
    }
    __syncthreads();
    unsigned wex = (tid >= 64) ? wsum[(tid >> 6) - 1] : 0u;
    unsigned incl = x + wex;       // inclusive pair-sum prefix at this thread
    unsigned E = incl - p;         // exclusive prefix before bin 2*tid
    if (E < K && E + a >= K)              { *out_b = 2 * tid;     *out_rem = (int)(K - E); }
    else if (E + a < K && E + a + b >= K) { *out_b = 2 * tid + 1; *out_rem = (int)(K - (E + a)); }
}

// K2b: find level-1 pivot bin b1 and residual rank K2
__global__ __launch_bounds__(1024) void k_pivot1(const unsigned* __restrict__ hist1,
                                                 int* __restrict__ piv) {
    int img = blockIdx.x;
    pivot_scan(hist1 + (size_t)img * HBLK * 2048, KCAND,
               &piv[img * 8 + 0], &piv[img * 8 + 1]);
}

// K2c: level-2 histogram (vkey bits [20:10]) restricted to elements in bin b1
__global__ __launch_bounds__(1024) void k_hist2(const float* __restrict__ scores,
                                                const int* __restrict__ piv,
                                                unsigned* __restrict__ hist2) {
    __shared__ unsigned hh[2048];
    int img = blockIdx.x >> 3, blk = blockIdx.x & 7;
    int tid = threadIdx.x;
    hh[tid] = 0; hh[tid + 1024] = 0;
    __syncthreads();
    unsigned b1 = (unsigned)piv[img * 8 + 0];
    const float* sc = scores + (size_t)img * NSCORE + (size_t)blk * HCHUNK;
    for (int e = tid; e < HCHUNK; e += 1024) {
        unsigned vk = score_vkey(sc[e]);
        if ((vk >> 21) == b1) atomicAdd(&hh[(vk >> 10) & 2047u], 1u);
    }
    __syncthreads();
    unsigned* outp = hist2 + ((size_t)img * HBLK + blk) * 2048;
    outp[tid] = hh[tid];
    outp[tid + 1024] = hh[tid + 1024];
}

// K2d: find level-2 pivot -> 22-bit threshold T22; zero the gather counter
__global__ __launch_bounds__(1024) void k_pivot2(const unsigned* __restrict__ hist2,
                                                 int* __restrict__ piv) {
    __shared__ int b2s, rem2s;
    int img = blockIdx.x;
    pivot_scan(hist2 + (size_t)img * HBLK * 2048, (unsigned)piv[img * 8 + 1], &b2s, &rem2s);
    __syncthreads();
    if (threadIdx.x == 0) {
        piv[img * 8 + 2] = (piv[img * 8 + 0] << 11) | b2s;  // T22
        piv[img * 8 + 3] = 0;                               // gather counter
    }
}

// K2e: gather all elements with top22(key) <= T22 (>=1024, ~1030 expected), unordered
__global__ __launch_bounds__(1024) void k_gathersel(const float* __restrict__ scores,
                                                    int* __restrict__ piv,
                                                    unsigned long long* __restrict__ cbuf) {
    __shared__ unsigned lcnt, gbase;
    int img = blockIdx.x >> 3, blk = blockIdx.x & 7;
    int tid = threadIdx.x;
    if (tid == 0) lcnt = 0;
    __syncthreads();
    unsigned T22 = (unsigned)piv[img * 8 + 2];
    const float* sc = scores + (size_t)img * NSCORE + (size_t)blk * HCHUNK;
    unsigned long long sel[(HCHUNK + 1023) / 1024];
    int ns = 0;
    for (int e = tid; e < HCHUNK; e += 1024) {
        unsigned vk = score_vkey(sc[e]);
        if ((vk >> 10) <= T22)
            sel[ns++] = ((unsigned long long)vk << 32) | (unsigned)(blk * HCHUNK + e);
    }
    unsigned lp = atomicAdd(&lcnt, (unsigned)ns);
    __syncthreads();
    if (tid == 0) gbase = atomicAdd((unsigned*)&piv[img * 8 + 3], lcnt);
    __syncthreads();
    unsigned long long* ob = cbuf + (size_t)img * 2048;
    for (int i = 0; i < ns; ++i) {
        unsigned pos = gbase + lp + (unsigned)i;
        if (pos < 2048) ob[pos] = sel[i];
    }
}

// K2f: rank-by-counting -> sorted top-1024 keys. 8 slice-blocks per image so 64
// CUs participate; loop bound cnt (~1030) not 2048. Broadcast LDS reads are
// conflict-free; keys unique so strict < gives the exact rank.
__global__ __launch_bounds__(256) void k_rank(const unsigned long long* __restrict__ cbuf,
                                              const int* __restrict__ piv,
                                              unsigned long long* __restrict__ candk) {
    __shared__ unsigned long long keys[2048];
    int img = blockIdx.x >> 3, sl = blockIdx.x & 7;
    int tid = threadIdx.x;
    int cnt = piv[img * 8 + 3]; if (cnt > 2048) cnt = 2048;
    const unsigned long long* ib = cbuf + (size_t)img * 2048;
    #pragma unroll
    for (int k = 0; k < 8; ++k) {
        int t = k * 256 + tid;
        keys[t] = (t < cnt) ? ib[t] : ~0ULL;
    }
    __syncthreads();
    unsigned long long a = keys[sl * 256 + tid];
    int r = 0;
    #pragma unroll 8
    for (int j = 0; j < cnt; ++j) r += (keys[j] < a) ? 1 : 0;
    if (r < KCAND) candk[(size_t)img * KCAND + r] = a;
}

// K4: candidate prep — clip, class offset, area (all _rn to match numpy per-op rounding)
__global__ __launch_bounds__(1024) void k_cand(const unsigned long long* __restrict__ candk,
                                               const float* __restrict__ boxes,
                                               const int* __restrict__ hw,
                                               float* __restrict__ cx1, float* __restrict__ cy1,
                                               float* __restrict__ cx2, float* __restrict__ cy2,
                                               float* __restrict__ car, int* __restrict__ cprop,
                                               unsigned long long* __restrict__ validw) {
    int bimg = blockIdx.x;
    int j    = threadIdx.x;
    unsigned long long key = candk[(size_t)bimg * KCAND + j];
    unsigned int u   = ~(unsigned int)(key >> 32);
    unsigned int idx = (unsigned int)key;
    const unsigned int uth = __float_as_uint(1e-4f) | 0x80000000u;
    bool valid = u > uth;
    int prop = (int)(idx / NCLS);
    int cls  = (int)(idx - (unsigned)prop * NCLS);
    const float4 bx = *(const float4*)(boxes + ((((size_t)bimg * NPROP + prop) * NCLS + cls) << 2));
    float h = (float)hw[bimg * 2 + 0];
    float w = (float)hw[bimg * 2 + 1];
    float x1 = fminf(fmaxf(bx.x, 0.f), w);
    float y1 = fminf(fmaxf(bx.y, 0.f), h);
    float x2 = fminf(fmaxf(bx.z, 0.f), w);
    float y2 = fminf(fmaxf(bx.w, 0.f), h);
    float offc = __fmul_rn((float)cls, 4096.0f);
    x1 = __fadd_rn(x1, offc); y1 = __fadd_rn(y1, offc);
    x2 = __fadd_rn(x2, offc); y2 = __fadd_rn(y2, offc);
    float area = __fmul_rn(__fsub_rn(x2, x1), __fsub_rn(y2, y1));
    int o = bimg * KCAND + j;
    cx1[o] = x1; cy1[o] = y1; cx2[o] = x2; cy2[o] = y2; car[o] = area; cprop[o] = prop;
    unsigned long long bal = __ballot(valid);
    if ((threadIdx.x & 63) == 0) validw[bimg * 16 + (j >> 6)] = bal;
}

// K5: per-row IoU -> transposed suppression masks, TRIANGULAR (c <= i>>6 only;
// upper chunks are provably all-zero and pre-zeroed by k_memz). Wave-wide gate:
// iou > th (th >= 0.001) requires inter > 0, and cross-class pairs always have
// inter == 0, so ~98% of chunks skip the div + 10 ballots and store nothing.
__global__ void k_masks(const float* __restrict__ cx1, const float* __restrict__ cy1,
                        const float* __restrict__ cx2, const float* __restrict__ cy2,
                        const float* __restrict__ car,
                        unsigned long long* __restrict__ masks) {
    int gw   = (blockIdx.x * blockDim.x + threadIdx.x) >> 6;  // global wave = row
    int lane = threadIdx.x & 63;
    if (gw >= NB * KCAND) return;
    int bimg = gw >> 10;
    int i    = gw & (KCAND - 1);
    int cb   = bimg * KCAND;
    float xi1 = cx1[cb + i], yi1 = cy1[cb + i];
    float xi2 = cx2[cb + i], yi2 = cy2[cb + i], ai = car[cb + i];
    int cmax = i >> 6;
    for (int c = 0; c <= cmax; ++c) {
        int j = c * 64 + lane;
        float xj1 = cx1[cb + j], yj1 = cy1[cb + j];
        float xj2 = cx2[cb + j], yj2 = cy2[cb + j], aj = car[cb + j];
        float iw = fmaxf(__fsub_rn(fminf(xi2, xj2), fmaxf(xi1, xj1)), 0.f);
        float ih = fmaxf(__fsub_rn(fminf(yi2, yj2), fmaxf(yi1, yj1)), 0.f);
        float inter = __fmul_rn(iw, ih);
        bool jlt = j < i;   // suppressors have smaller index
        if (__ballot(jlt && (inter > 0.f)) == 0ULL) continue;  // all 10 masks zero
        float uni = __fsub_rn(__fadd_rn(ai, aj), inter);
        float iou = (uni > 0.f) ? __fdiv_rn(inter, uni) : 0.f;
        unsigned long long bl[NTH];
        #pragma unroll
        for (int t = 0; t < NTH; ++t) bl[t] = __ballot(jlt && (iou > nms_th(t)));
        unsigned long long myv = 0;
        #pragma unroll
        for (int t = 0; t < NTH; ++t) myv = (lane == t) ? bl[t] : myv;
        if (lane < NTH)
            masks[(size_t)lane * TSTRIDE + (((size_t)(bimg * 16 + c)) << 10) + i] = myv;
    }
}

// K6: greedy NMS via Jacobi fixed-point iteration (exact greedy fixed point).
// Triangular masks: row i only has suppressor words for c <= i>>6.
__global__ __launch_bounds__(1024) void k_scan(const unsigned long long* __restrict__ masks,
                                               const unsigned long long* __restrict__ validw,
                                               unsigned long long* __restrict__ keeps,
                                               int* __restrict__ counts) {
    __shared__ unsigned long long kp[16];
    __shared__ int changed[2];
    int bt   = blockIdx.x;
    int bimg = bt / NTH, t = bt % NTH;
    int tid  = threadIdx.x;
    int w    = tid >> 6;
    int lane = tid & 63;
    const unsigned long long* mb = masks + (size_t)t * TSTRIDE + ((size_t)(bimg * 16) << 10);
    unsigned long long row[16];
    #pragma unroll
    for (int c = 0; c < 16; ++c)
        row[c] = (c <= w) ? mb[((size_t)c << 10) + tid] : 0ULL;
    unsigned long long vw = validw[bimg * 16 + w];
    bool valid = (vw >> lane) & 1ULL;
    if (tid < 16) kp[tid] = validw[bimg * 16 + tid];
    if (tid < 2) changed[tid] = 0;
    __syncthreads();
    for (int iter = 0; iter < KCAND + 2; ++iter) {
        unsigned long long s = 0;
        #pragma unroll
        for (int c = 0; c < 16; ++c) s |= row[c] & kp[c];
        bool nk = valid && (s == 0);
        unsigned long long bal = __ballot(nk);
        bool diff = (lane == 0) && (bal != kp[w]);
        __syncthreads();
        if (diff) { kp[w] = bal; changed[iter & 1] = 1; }
        if (tid == 0) changed[(iter + 1) & 1] = 0;
        __syncthreads();
        if (!changed[iter & 1]) break;
    }
    if (tid < 16) keeps[((size_t)bimg * NTH + t) * 16 + tid] = kp[tid];
    if (tid < 64) {
        int c = (lane < 16) ? __popcll(kp[lane]) : 0;
        #pragma unroll
        for (int o = 32; o > 0; o >>= 1) c += __shfl_xor(c, o, 64);
        if (lane == 0) counts[bimg * NTH + t] = c;
    }
}

// K7: pick first threshold with count>=6 (else last), take first-6 kept (fill with
// lowest-index non-kept if fewer, matching top_k tie order on -inf)
__global__ void k_select(const int* __restrict__ counts,
                         const unsigned long long* __restrict__ keeps,
                         const int* __restrict__ cprop, int* __restrict__ ids) {
    int bimg = blockIdx.x;
    if (threadIdx.x != 0) return;
    int tsel = NTH - 1;
    for (int t = 0; t < NTH; ++t) {
        if (counts[bimg * NTH + t] >= NOBJ) { tsel = t; break; }
    }
    const unsigned long long* kw = keeps + ((size_t)bimg * NTH + tsel) * 16;
    int got = 0;
    for (int k = 0; k < 16 && got < NOBJ; ++k) {
        unsigned long long x = kw[k];
        while (x && got < NOBJ) {
            int b = __builtin_ctzll(x);
            ids[bimg * NOBJ + got] = cprop[bimg * KCAND + k * 64 + b];
            ++got;
            x &= x - 1;
        }
    }
    for (int k = 0; k < 16 && got < NOBJ; ++k) {
        unsigned long long x = ~kw[k];
        while (x && got < NOBJ) {
            int b = __builtin_ctzll(x);
            ids[bimg * NOBJ + got] = cprop[bimg * KCAND + k * 64 + b];
            ++got;
            x &= x - 1;
        }
    }
}

// K8: out[b, d, s] = feats[b, ids[s], d]
__global__ void k_featgather(const float* __restrict__ feats, const int* __restrict__ ids,
                             float* __restrict__ outp) {
    int g = blockIdx.x * blockDim.x + threadIdx.x;
    if (g >= NB * DFEAT) return;
    int bimg = g / DFEAT;
    int d    = g - bimg * DFEAT;
    const float* fb = feats + (size_t)bimg * NPROP * DFEAT;
    float* ob = outp + ((size_t)bimg * DFEAT + d) * NOBJ;
    #pragma unroll
    for (int s = 0; s < NOBJ; ++s) {
        int id = ids[bimg * NOBJ + s];
        ob[s] = fb[(size_t)id * DFEAT + d];
    }
}

extern "C" void kernel_launch(void* const* d_in, const int* in_sizes, int n_in,
                              void* d_out, int out_size, void* d_ws, size_t ws_size,
                              hipStream_t stream) {
    const float* logits = (const float*)d_in[0];
    const float* boxes  = (const float*)d_in[1];
    const float* feats  = (const float*)d_in[2];
    const int*   hw     = (const int*)d_in[3];
    float* outp = (float*)d_out;

    char* ws = (char*)d_ws;
    float*              scores = (float*)(ws + OFF_SCORES);
    unsigned*           hist1  = (unsigned*)(ws + OFF_H1);
    unsigned*           hist2  = (unsigned*)(ws + OFF_H2);
    int*                piv    = (int*)(ws + OFF_PIV);
    unsigned long long* cbuf   = (unsigned long long*)(ws + OFF_CBUF);
    unsigned long long* candk  = (unsigned long long*)(ws + OFF_CANDK);
    float* cx1 = (float*)(ws + OFF_CX1);
    float* cy1 = (float*)(ws + OFF_CY1);
    float* cx2 = (float*)(ws + OFF_CX2);
    float* cy2 = (float*)(ws + OFF_CY2);
    float* car = (float*)(ws + OFF_CAREA);
    int*   cprop = (int*)(ws + OFF_CPROP);
    unsigned long long* validw = (unsigned long long*)(ws + OFF_VALIDW);
    unsigned long long* masks  = (unsigned long long*)(ws + OFF_MASKS);
    unsigned long long* keeps  = (unsigned long long*)(ws + OFF_KEEPS);
    int* counts = (int*)(ws + OFF_COUNTS);
    int* ids    = (int*)(ws + OFF_IDS);

    const int mz_n = (int)(SZ_MASKS / 16);  // ulonglong2 count
    k_memz<<<(mz_n + 255) / 256, 256, 0, stream>>>((ulonglong2*)masks, mz_n);
    k_softmax<<<(NB * NPROP) / 4, 256, 0, stream>>>(logits, scores);
    k_hist1<<<NB * HBLK, 1024, 0, stream>>>(scores, hist1);
    k_pivot1<<<NB, 1024, 0, stream>>>(hist1, piv);
    k_hist2<<<NB * HBLK, 1024, 0, stream>>>(scores, piv, hist2);
    k_pivot2<<<NB, 1024, 0, stream>>>(hist2, piv);
    k_gathersel<<<NB * HBLK, 1024, 0, stream>>>(scores, piv, cbuf);
    k_rank<<<NB * HBLK, 256, 0, stream>>>(cbuf, piv, candk);
    k_cand<<<NB, 1024, 0, stream>>>(candk, boxes, hw, cx1, cy1, cx2, cy2, car, cprop, validw);
    k_masks<<<(NB * KCAND) / 4, 256, 0, stream>>>(cx1, cy1, cx2, cy2, car, masks);
    k_scan<<<NB * NTH, 1024, 0, stream>>>(masks, validw, keeps, counts);
    k_select<<<NB, 64, 0, stream>>>(counts, keeps, cprop, ids);
    k_featgather<<<(NB * DFEAT + 255) / 256, 256, 0, stream>>>(feats, ids, outp);
}